// Round 8
// baseline (112.944 us; speedup 1.0000x reference)
//
#include <hip/hip_runtime.h>

// Problem dims (fixed): S=256, BT=32, D=128, N=128, O=128
#define S_DIM 256
#define BT_DIM 32
#define D_DIM 128
#define N_DIM 128
#define O_DIM 128
#define SB (S_DIM * BT_DIM)   // 8192 flattened (s,b) rows
#define EPS 1e-7f

typedef short s16x8 __attribute__((ext_vector_type(8)));  // 8 bf16 (4 VGPRs)
typedef float fx4   __attribute__((ext_vector_type(4)));

union U8 { unsigned short u[8]; s16x8 v; };

__device__ __forceinline__ unsigned short f2bf(float f) {
    unsigned u = __builtin_bit_cast(unsigned, f);
    return (unsigned short)((u + 0x7fffu + ((u >> 16) & 1u)) >> 16);  // RNE
}
__device__ __forceinline__ float bf2f(unsigned short h) {
    unsigned u = ((unsigned)h) << 16;
    return __builtin_bit_cast(float, u);
}
// 8 fp32 -> bf16 (hi only)
__device__ __forceinline__ s16x8 cvt8hi(const float4 f0, const float4 f1) {
    float f[8] = {f0.x, f0.y, f0.z, f0.w, f1.x, f1.y, f1.z, f1.w};
    U8 h;
    #pragma unroll
    for (int i = 0; i < 8; ++i) h.u[i] = f2bf(f[i]);
    return h.v;
}
// 8 fp32 -> bf16 hi + lo fragments
__device__ __forceinline__ void cvt8(const float4 f0, const float4 f1, s16x8& hi, s16x8& lo) {
    float f[8] = {f0.x, f0.y, f0.z, f0.w, f1.x, f1.y, f1.z, f1.w};
    U8 h, l;
    #pragma unroll
    for (int i = 0; i < 8; ++i) {
        unsigned short hb = f2bf(f[i]);
        h.u[i] = hb;
        l.u[i] = f2bf(f[i] - bf2f(hb));
    }
    hi = h.v; lo = l.v;
}
// 4 fp32 -> bf16 hi + lo packed pairs
__device__ __forceinline__ void pack4(const float4 f, unsigned* hi2, unsigned* lo2) {
    float f_[4] = {f.x, f.y, f.z, f.w};
    unsigned short hb[4], lb[4];
    #pragma unroll
    for (int i = 0; i < 4; ++i) {
        hb[i] = f2bf(f_[i]);
        lb[i] = f2bf(f_[i] - bf2f(hb[i]));
    }
    hi2[0] = (unsigned)hb[0] | ((unsigned)hb[1] << 16);
    hi2[1] = (unsigned)hb[2] | ((unsigned)hb[3] << 16);
    lo2[0] = (unsigned)lb[0] | ((unsigned)lb[1] << 16);
    lo2[1] = (unsigned)lb[2] | ((unsigned)lb[3] << 16);
}

// ---------------------------------------------------------------------------
// Fused kernel, 256 blocks x 256 thr = (b 32) x (nt 8).
// Phase P (all blocks): Bx-tile = X@B^T (split-bf16 MFMA) -> two-level scan
//   -> hs_hi (bf16, [s][b][n]) + hT.
// Ticket: per-b atomic counter (zeroed by memsetAsync); 8th arriver of each b
//   becomes the consumer -- no spinning, deadlock-free under any dispatch order.
// Phase C (32 consumer blocks): out rows of b = hs @ C^T; C slice converted
//   to split-bf16 in registers (2 o-tiles per wave, frags live across s-tiles).
// ---------------------------------------------------------------------------
__global__ __launch_bounds__(256) void fused_lru(const float* __restrict__ X,
                                                 const float* __restrict__ lamlog,
                                                 const float* __restrict__ Bm,
                                                 const float* __restrict__ Cm,
                                                 unsigned* __restrict__ cnt,
                                                 unsigned short* __restrict__ hs_hi,
                                                 float* __restrict__ out,
                                                 float* __restrict__ hT) {
    __shared__ unsigned short Bhi[16][136];
    __shared__ unsigned short Blo[16][136];
    __shared__ float Bxs[S_DIM][17];
    __shared__ float carr[16][17];
    __shared__ int is_last;

    const int t  = threadIdx.x;
    const int b  = blockIdx.x >> 3;
    const int n0 = (blockIdx.x & 7) * 16;

    // ---- Phase P: stage + convert B tile (rows n0..n0+15), coalesced ----
    #pragma unroll
    for (int q = 0; q < 2; ++q) {
        const int id4 = t + 256 * q;
        const int row = id4 >> 5, c4 = id4 & 31;
        const float4 f = *reinterpret_cast<const float4*>(Bm + (size_t)(n0 + row) * D_DIM + c4 * 4);
        unsigned hi2[2], lo2[2];
        pack4(f, hi2, lo2);
        *reinterpret_cast<uint2*>(&Bhi[row][c4 * 4]) = make_uint2(hi2[0], hi2[1]);
        *reinterpret_cast<uint2*>(&Blo[row][c4 * 4]) = make_uint2(lo2[0], lo2[1]);
    }
    __syncthreads();

    const int w  = t >> 6, l = t & 63;
    const int lr = l & 15;            // frag row
    const int lk = (l >> 4) * 8;      // frag k-offset base

    {
        s16x8 bh[4], bl[4];
        #pragma unroll
        for (int sl = 0; sl < 4; ++sl) {
            bh[sl] = *reinterpret_cast<const s16x8*>(&Bhi[lr][sl * 32 + lk]);
            bl[sl] = *reinterpret_cast<const s16x8*>(&Blo[lr][sl * 32 + lk]);
        }

        const float* __restrict__ xb = X + (size_t)b * D_DIM;
        #pragma unroll
        for (int q = 0; q < 4; ++q) {
            const int s0 = (w * 4 + q) * 16;
            const float* __restrict__ xr = xb + (size_t)(s0 + lr) * (BT_DIM * D_DIM);
            s16x8 ah[4];
            #pragma unroll
            for (int sl = 0; sl < 4; ++sl) {
                const float4 f0 = *reinterpret_cast<const float4*>(xr + sl * 32 + lk);
                const float4 f1 = *reinterpret_cast<const float4*>(xr + sl * 32 + lk + 4);
                ah[sl] = cvt8hi(f0, f1);
            }
            fx4 acc = {0.f, 0.f, 0.f, 0.f};
            #pragma unroll
            for (int sl = 0; sl < 4; ++sl) {
                acc = __builtin_amdgcn_mfma_f32_16x16x32_bf16(ah[sl], bh[sl], acc, 0, 0, 0);
                acc = __builtin_amdgcn_mfma_f32_16x16x32_bf16(ah[sl], bl[sl], acc, 0, 0, 0);
            }
            #pragma unroll
            for (int r = 0; r < 4; ++r)
                Bxs[s0 + (l >> 4) * 4 + r][lr] = acc[r];
        }
    }
    __syncthreads();

    // ---- Two-level scan: 256 tasks (j = n-within-tile, c = 16-step chunk) ----
    {
        const int j = t & 15;
        const int c = t >> 4;
        const float ll    = lamlog[n0 + j];
        const float lam   = expf(-expf(ll));
        const float gamma = sqrtf(1.f - lam * lam + EPS);
        const float l2 = lam * lam, l4 = l2 * l2, l8 = l4 * l4;
        const float lam16 = l8 * l8;

        float h = 0.f;
        #pragma unroll
        for (int i = 0; i < 16; ++i)
            h = fmaf(lam, h, gamma * Bxs[c * 16 + i][j]);
        carr[c][j] = h;
        __syncthreads();

        float Hb = 0.f;
        for (int cp = 0; cp < c; ++cp)
            Hb = fmaf(lam16, Hb, carr[cp][j]);

        h = Hb;
        #pragma unroll
        for (int i = 0; i < 16; ++i) {
            h = fmaf(lam, h, gamma * Bxs[c * 16 + i][j]);
            const size_t rg = (size_t)(c * 16 + i) * BT_DIM + b;     // global row
            hs_hi[rg * N_DIM + n0 + j] = f2bf(h);
        }
        if (c == 15) hT[b * N_DIM + n0 + j] = h;
    }

    // ---- Ticket: release fence, per-b count; 8th arriver consumes ----
    __syncthreads();                 // all waves' stores drained (vmcnt 0)
    __threadfence();                 // device-scope release (L2 writeback)
    __syncthreads();
    if (t == 0) is_last = (atomicAdd(&cnt[b], 1u) == 7u) ? 1 : 0;
    __syncthreads();
    if (!is_last) return;
    __threadfence();                 // device-scope acquire (invalidate)

    // ---- Phase C: out rows of b = hs @ C^T (split-bf16, C in registers) ----
    // Wave w owns o-tiles {2w, 2w+1}; C-frags converted once, reused 16x.
    s16x8 ch[2][4], cl[2][4];
    #pragma unroll
    for (int j2 = 0; j2 < 2; ++j2) {
        const int o0 = (2 * w + j2) * 16;
        const float* __restrict__ cr = Cm + (size_t)(o0 + lr) * N_DIM;
        #pragma unroll
        for (int sl = 0; sl < 4; ++sl) {
            const float4 f0 = *reinterpret_cast<const float4*>(cr + sl * 32 + lk);
            const float4 f1 = *reinterpret_cast<const float4*>(cr + sl * 32 + lk + 4);
            cvt8(f0, f1, ch[j2][sl], cl[j2][sl]);
        }
    }

    for (int q16 = 0; q16 < 16; ++q16) {
        const unsigned short* __restrict__ hr =
            hs_hi + ((size_t)(q16 * 16 + lr) * BT_DIM + b) * N_DIM;
        s16x8 ah[4];
        #pragma unroll
        for (int sl = 0; sl < 4; ++sl)
            ah[sl] = *reinterpret_cast<const s16x8*>(&hr[sl * 32 + lk]);

        #pragma unroll
        for (int j2 = 0; j2 < 2; ++j2) {
            fx4 acc = {0.f, 0.f, 0.f, 0.f};
            #pragma unroll
            for (int sl = 0; sl < 4; ++sl) {
                acc = __builtin_amdgcn_mfma_f32_16x16x32_bf16(ah[sl], ch[j2][sl], acc, 0, 0, 0);
                acc = __builtin_amdgcn_mfma_f32_16x16x32_bf16(ah[sl], cl[j2][sl], acc, 0, 0, 0);
            }
            const int o0 = (2 * w + j2) * 16;
            const int sw = q16 * 16 + (l >> 4) * 4;
            #pragma unroll
            for (int r = 0; r < 4; ++r)
                out[((size_t)(sw + r) * BT_DIM + b) * O_DIM + o0 + lr] = acc[r];
        }
    }
}

extern "C" void kernel_launch(void* const* d_in, const int* in_sizes, int n_in,
                              void* d_out, int out_size, void* d_ws, size_t ws_size,
                              hipStream_t stream) {
    const float* x          = (const float*)d_in[0];  // [S][BT][D]
    const float* lambda_log = (const float*)d_in[1];  // [N]
    const float* B          = (const float*)d_in[2];  // [N][D]
    const float* C          = (const float*)d_in[3];  // [O][N]

    float* out = (float*)d_out;                       // [S][BT][O] then hT [BT][N]
    float* hT  = out + (size_t)SB * O_DIM;

    unsigned* cnt = (unsigned*)d_ws;                              // 32 counters (128 B)
    unsigned short* hs_hi = (unsigned short*)((char*)d_ws + 256); // [SB][N] bf16, 2 MB

    hipMemsetAsync(cnt, 0, 128, stream);              // zero tickets (re-poisoned each call)
    fused_lru<<<256, 256, 0, stream>>>(x, lambda_log, B, C, cnt, hs_hi, out, hT);
}

// Round 9
// 74.499 us; speedup vs baseline: 1.5160x; 1.5160x over previous
//
#include <hip/hip_runtime.h>

// Problem dims (fixed): S=256, BT=32, D=128, N=128, O=128
#define S_DIM 256
#define BT_DIM 32
#define D_DIM 128
#define N_DIM 128
#define O_DIM 128
#define SB (S_DIM * BT_DIM)   // 8192 flattened (s,b) rows
#define EPS 1e-7f

typedef short s16x8 __attribute__((ext_vector_type(8)));  // 8 bf16 (4 VGPRs)
typedef float fx4   __attribute__((ext_vector_type(4)));

union U8 { unsigned short u[8]; s16x8 v; };

__device__ __forceinline__ unsigned short f2bf(float f) {
    unsigned u = __builtin_bit_cast(unsigned, f);
    return (unsigned short)((u + 0x7fffu + ((u >> 16) & 1u)) >> 16);  // RNE
}
__device__ __forceinline__ float bf2f(unsigned short h) {
    unsigned u = ((unsigned)h) << 16;
    return __builtin_bit_cast(float, u);
}
// 8 fp32 -> bf16 (hi only)
__device__ __forceinline__ s16x8 cvt8hi(const float4 f0, const float4 f1) {
    float f[8] = {f0.x, f0.y, f0.z, f0.w, f1.x, f1.y, f1.z, f1.w};
    U8 h;
    #pragma unroll
    for (int i = 0; i < 8; ++i) h.u[i] = f2bf(f[i]);
    return h.v;
}
// 4 fp32 -> bf16 hi + lo packed pairs
__device__ __forceinline__ void pack4(const float4 f, unsigned* hi2, unsigned* lo2) {
    float f_[4] = {f.x, f.y, f.z, f.w};
    unsigned short hb[4], lb[4];
    #pragma unroll
    for (int i = 0; i < 4; ++i) {
        hb[i] = f2bf(f_[i]);
        lb[i] = f2bf(f_[i] - bf2f(hb[i]));
    }
    hi2[0] = (unsigned)hb[0] | ((unsigned)hb[1] << 16);
    hi2[1] = (unsigned)hb[2] | ((unsigned)hb[3] << 16);
    lo2[0] = (unsigned)lb[0] | ((unsigned)lb[1] << 16);
    lo2[1] = (unsigned)lb[2] | ((unsigned)lb[3] << 16);
}

// ---------------------------------------------------------------------------
// K1: Bx = X @ B^T (split-bf16 MFMA: Xhi*Bhi + Xhi*Blo) -> two-level scan.
// Blocks 0..255: (b 32) x (nt 8), 512 thr = 8 waves (2 waves/SIMD for latency
// hiding); wave w owns s-tiles {2w, 2w+1}. hs stored bf16 row-major [r][n].
// Blocks 256..263: one-time C -> bf16 hi/lo conversion into ws (for K2).
// ---------------------------------------------------------------------------
__global__ __launch_bounds__(512) void k1_gemm_scan(const float* __restrict__ X,
                                                    const float* __restrict__ lamlog,
                                                    const float* __restrict__ Bm,
                                                    const float* __restrict__ Cm,
                                                    unsigned short* __restrict__ hs_hi,
                                                    unsigned short* __restrict__ Chi,
                                                    unsigned short* __restrict__ Clo,
                                                    float* __restrict__ hT) {
    const int t = threadIdx.x;

    if (blockIdx.x >= 256) {
        // C-convert: 8 blocks x 512 thr x 4 elems = 16384 = 128*128.
        const int id = (blockIdx.x - 256) * 512 + t;            // 0..4095
        const float4 f = reinterpret_cast<const float4*>(Cm)[id];
        unsigned hi2[2], lo2[2];
        pack4(f, hi2, lo2);
        *reinterpret_cast<uint2*>(Chi + (size_t)id * 4) = make_uint2(hi2[0], hi2[1]);
        *reinterpret_cast<uint2*>(Clo + (size_t)id * 4) = make_uint2(lo2[0], lo2[1]);
        return;
    }

    __shared__ unsigned short Bhi[16][136];
    __shared__ unsigned short Blo[16][136];
    __shared__ float Bxs[S_DIM][17];
    __shared__ float carr[16][17];

    const int b  = blockIdx.x >> 3;
    const int n0 = (blockIdx.x & 7) * 16;

    // Stage + convert B tile (rows n0..n0+15): 512 float4, 1/thread, coalesced.
    {
        const int row = t >> 5, c4 = t & 31;
        const float4 f = *reinterpret_cast<const float4*>(Bm + (size_t)(n0 + row) * D_DIM + c4 * 4);
        unsigned hi2[2], lo2[2];
        pack4(f, hi2, lo2);
        *reinterpret_cast<uint2*>(&Bhi[row][c4 * 4]) = make_uint2(hi2[0], hi2[1]);
        *reinterpret_cast<uint2*>(&Blo[row][c4 * 4]) = make_uint2(lo2[0], lo2[1]);
    }
    __syncthreads();

    const int w  = t >> 6, l = t & 63;   // w: 0..7
    const int lr = l & 15;               // frag row
    const int lk = (l >> 4) * 8;         // frag k-offset base

    {
        s16x8 bh[4], bl[4];
        #pragma unroll
        for (int sl = 0; sl < 4; ++sl) {
            bh[sl] = *reinterpret_cast<const s16x8*>(&Bhi[lr][sl * 32 + lk]);
            bl[sl] = *reinterpret_cast<const s16x8*>(&Blo[lr][sl * 32 + lk]);
        }

        const float* __restrict__ xb = X + (size_t)b * D_DIM;
        #pragma unroll
        for (int q = 0; q < 2; ++q) {
            const int s0 = (w * 2 + q) * 16;
            const float* __restrict__ xr = xb + (size_t)(s0 + lr) * (BT_DIM * D_DIM);
            s16x8 ah[4];
            #pragma unroll
            for (int sl = 0; sl < 4; ++sl) {
                const float4 f0 = *reinterpret_cast<const float4*>(xr + sl * 32 + lk);
                const float4 f1 = *reinterpret_cast<const float4*>(xr + sl * 32 + lk + 4);
                ah[sl] = cvt8hi(f0, f1);
            }
            fx4 acc = {0.f, 0.f, 0.f, 0.f};
            #pragma unroll
            for (int sl = 0; sl < 4; ++sl) {
                acc = __builtin_amdgcn_mfma_f32_16x16x32_bf16(ah[sl], bh[sl], acc, 0, 0, 0);
                acc = __builtin_amdgcn_mfma_f32_16x16x32_bf16(ah[sl], bl[sl], acc, 0, 0, 0);
            }
            #pragma unroll
            for (int r = 0; r < 4; ++r)
                Bxs[s0 + (l >> 4) * 4 + r][lr] = acc[r];
        }
    }
    __syncthreads();

    // Two-level scan: 256 tasks on waves 0..3 (j = n-within-tile, c = chunk).
    const int j = t & 15;
    const int c = (t >> 4) & 15;
    float lam = 0.f, gamma = 0.f, lam16 = 0.f;
    if (t < 256) {
        const float ll = lamlog[n0 + j];
        lam   = expf(-expf(ll));
        gamma = sqrtf(1.f - lam * lam + EPS);
        const float l2 = lam * lam, l4 = l2 * l2, l8 = l4 * l4;
        lam16 = l8 * l8;

        float h = 0.f;
        #pragma unroll
        for (int i = 0; i < 16; ++i)
            h = fmaf(lam, h, gamma * Bxs[c * 16 + i][j]);
        carr[c][j] = h;
    }
    __syncthreads();
    if (t < 256) {
        float Hb = 0.f;
        for (int cp = 0; cp < c; ++cp)
            Hb = fmaf(lam16, Hb, carr[cp][j]);

        float h = Hb;
        #pragma unroll
        for (int i = 0; i < 16; ++i) {
            h = fmaf(lam, h, gamma * Bxs[c * 16 + i][j]);
            const size_t rg = (size_t)(c * 16 + i) * BT_DIM + b;     // global row
            hs_hi[rg * N_DIM + n0 + j] = f2bf(h);
        }
        if (c == 15) hT[b * N_DIM + n0 + j] = h;
    }
}

// ---------------------------------------------------------------------------
// K2: out = hs @ C^T  (hs_hi * Chi + hs_hi * Clo), no LDS, no conversion.
// 256 blocks x 512 thr (8 waves, 2/SIMD); block = 32 rows x 128 o.
// Wave w: row-tile (w&1), o-tiles {(w>>1)*2, (w>>1)*2+1}.
// All fragments from global (hs_hi 2 MB, Chi/Clo 32 KB each: L2-resident).
// ---------------------------------------------------------------------------
__global__ __launch_bounds__(512) void k2_outgemm(const unsigned short* __restrict__ hs_hi,
                                                  const unsigned short* __restrict__ Chi,
                                                  const unsigned short* __restrict__ Clo,
                                                  float* __restrict__ out) {
    const int t  = threadIdx.x;
    const int r0 = blockIdx.x * 32;
    const int w  = t >> 6, l = t & 63;
    const int lr = l & 15;
    const int lk = (l >> 4) * 8;
    const int rt = w & 1;
    const int rbase = r0 + 16 * rt + lr;

    // A-fragments from hs_hi (row-major bf16): contiguous 16 B per lane.
    s16x8 ah[4];
    #pragma unroll
    for (int sl = 0; sl < 4; ++sl)
        ah[sl] = *reinterpret_cast<const s16x8*>(&hs_hi[(size_t)rbase * N_DIM + sl * 32 + lk]);

    #pragma unroll
    for (int q = 0; q < 2; ++q) {
        const int o0 = ((w >> 1) * 2 + q) * 16;
        fx4 acc = {0.f, 0.f, 0.f, 0.f};
        #pragma unroll
        for (int sl = 0; sl < 4; ++sl) {
            const s16x8 bh = *reinterpret_cast<const s16x8*>(&Chi[(size_t)(o0 + lr) * N_DIM + sl * 32 + lk]);
            const s16x8 bl = *reinterpret_cast<const s16x8*>(&Clo[(size_t)(o0 + lr) * N_DIM + sl * 32 + lk]);
            acc = __builtin_amdgcn_mfma_f32_16x16x32_bf16(ah[sl], bh, acc, 0, 0, 0);
            acc = __builtin_amdgcn_mfma_f32_16x16x32_bf16(ah[sl], bl, acc, 0, 0, 0);
        }
        const int rw = r0 + 16 * rt + (l >> 4) * 4;
        #pragma unroll
        for (int r = 0; r < 4; ++r)
            out[(size_t)(rw + r) * O_DIM + o0 + lr] = acc[r];
    }
}

extern "C" void kernel_launch(void* const* d_in, const int* in_sizes, int n_in,
                              void* d_out, int out_size, void* d_ws, size_t ws_size,
                              hipStream_t stream) {
    const float* x          = (const float*)d_in[0];  // [S][BT][D]
    const float* lambda_log = (const float*)d_in[1];  // [N]
    const float* B          = (const float*)d_in[2];  // [N][D]
    const float* C          = (const float*)d_in[3];  // [O][N]

    float* out = (float*)d_out;                       // [S][BT][O] then hT [BT][N]
    float* hT  = out + (size_t)SB * O_DIM;

    unsigned short* hs_hi = (unsigned short*)d_ws;            // [SB][N] bf16, 2 MB
    unsigned short* Chi   = hs_hi + (size_t)SB * N_DIM;       // [O][N] bf16, 32 KB
    unsigned short* Clo   = Chi + O_DIM * N_DIM;              // [O][N] bf16, 32 KB

    // K1 (+8 tail blocks pre-converting C for K2)
    k1_gemm_scan<<<264, 512, 0, stream>>>(x, lambda_log, B, C, hs_hi, Chi, Clo, hT);
    // K2
    k2_outgemm<<<256, 512, 0, stream>>>(hs_hi, Chi, Clo, out);
}